// Round 1
// baseline (77.728 us; speedup 1.0000x reference)
//
#include <hip/hip_runtime.h>
#include <float.h>

// ChamferLoss via MFMA, R11: verts-in-registers, points-streamed-from-global.
// B=4, N=16384, M=4096, fp32 in/out.
// loss[b] = (1/N) * sum_n min_m max(||p_bn - v_bm||^2, 0)
//
// d2 = pp + (v2 - 2 p.v). Bracket on the MATRIX pipe via split-bf16 in K=16
// of mfma_f32_32x32x16_bf16 (encoding validated R6-R10, absmax 0.0):
//   A row (VERT):   [-2vh x3, -2vh x3, -2vl x3, v2h, v2l, 0...]
//   B col (POINT):  [ph x3, pl x3, ph x3, 1, 1, 0...]
//
// R11 key change: the old main loop paid 1 ds_read_b128 (12 cyc/CU) per MFMA
// (8.07 cyc/CU) -> LDS-bound, plus staging barriers and an un-pipelined
// ds_read->MFMA->min3 chain (~28us vs 3.4us MFMA floor). Now each wave holds
// 8 vert A-frags (256 verts) in VGPRs, loaded ONCE, and streams point B-frags
// (precomputed table, 2 MB, L2-resident) with one global_load_dwordx4 per
// 8 MFMAs. No LDS, no __syncthreads in the main kernel; 32 independent MFMAs
// per wave. pp is applied in the reduce (exact: +pp commutes with min).

typedef __bf16 bf16x8 __attribute__((ext_vector_type(8)));
typedef float  f32x16 __attribute__((ext_vector_type(16)));

constexpr int B = 4, N = 16384, M = 4096;
constexpr int BN = B * N;                 // 65536 points total
constexpr int VT = 8;                     // vert tiles (32 verts) held per wave
constexpr int NVC = M / (VT * 32);        // 16 vert-chunks of 256
constexpr int G = 4;                      // point-groups (32 pts) per wave
constexpr int TPB = 256;                  // 4 independent waves
constexpr int PPB = 4 * G * 32;           // 512 points per block
constexpr int NPB = BN / PPB;             // 128 point-blocks

// ws layout (16B-aligned slabs)
constexpr size_t VFRAG_BYTES = (size_t)B * M * 32;   // 512 KB vert A-frags
constexpr size_t PFRAG_BYTES = (size_t)BN * 32;      // 2 MB point B-frags
constexpr size_t PP_BYTES    = (size_t)BN * 4;       // 256 KB point self-dots
// partial: NVC * BN * 4 = 4 MB after the above

// ---- Pre-pass: vert A-frag K-vectors, point B-frag K-vectors, pp; zero out.
// Vert m of batch b -> byte offset b*131072 + (m>>5)*1024 + khalf*512 + (m&31)*16
// Point i (linear over BN) -> byte offset (i>>5)*1024 + khalf*512 + (i&31)*16
__global__ __launch_bounds__(256) void chamfer_pre(
    const float* __restrict__ src, const float* __restrict__ tv,
    unsigned char* __restrict__ vfr, unsigned char* __restrict__ pfr,
    float* __restrict__ pp, float* __restrict__ out)
{
    if (blockIdx.x == 0 && threadIdx.x < B) out[threadIdx.x] = 0.0f;
    __bf16 one = (__bf16)1.0f, zero = (__bf16)0.0f;

    if (blockIdx.x < (B * M) / 256) {
        // ---- vert path (identical bytes to the R10-validated encoding) ----
        int i = blockIdx.x * 256 + threadIdx.x;          // 0..B*M-1
        float x = tv[3 * i + 0], y = tv[3 * i + 1], z = tv[3 * i + 2];
        __bf16 xh = (__bf16)x, yh = (__bf16)y, zh = (__bf16)z;
        float xhf = (float)xh, yhf = (float)yh, zhf = (float)zh;
        __bf16 xl = (__bf16)(x - xhf), yl = (__bf16)(y - yhf), zl = (__bf16)(z - zhf);
        float v2 = fmaf(x, x, fmaf(y, y, z * z));
        __bf16 v2h = (__bf16)v2;
        __bf16 v2l = (__bf16)(v2 - (float)v2h);

        bf16x8 h0, h1;
        h0[0] = (__bf16)(-2.0f * xhf); h0[1] = (__bf16)(-2.0f * yhf);
        h0[2] = (__bf16)(-2.0f * zhf);
        h0[3] = h0[0]; h0[4] = h0[1]; h0[5] = h0[2];
        h0[6] = (__bf16)(-2.0f * (float)xl); h0[7] = (__bf16)(-2.0f * (float)yl);
        h1[0] = (__bf16)(-2.0f * (float)zl); h1[1] = v2h; h1[2] = v2l;
        h1[3] = zero; h1[4] = zero; h1[5] = zero; h1[6] = zero; h1[7] = zero;

        int m = i & (M - 1);
        size_t base = (size_t)(i >> 12) * 131072 + (size_t)(m >> 5) * 1024
                    + (size_t)(m & 31) * 16;
        *(bf16x8*)(vfr + base)       = h0;
        *(bf16x8*)(vfr + base + 512) = h1;
    } else {
        // ---- point path: B-frag encoding (same as R10's in-reg bP) ----
        int i = (blockIdx.x - (B * M) / 256) * 256 + threadIdx.x;  // 0..BN-1
        float x = src[3 * i + 0], y = src[3 * i + 1], z = src[3 * i + 2];
        __bf16 xh = (__bf16)x, yh = (__bf16)y, zh = (__bf16)z;
        __bf16 xl = (__bf16)(x - (float)xh), yl = (__bf16)(y - (float)yh),
               zl = (__bf16)(z - (float)zh);
        bf16x8 h0, h1;
        h0[0] = xh; h0[1] = yh; h0[2] = zh; h0[3] = xl;
        h0[4] = yl; h0[5] = zl; h0[6] = xh; h0[7] = yh;
        h1[0] = zh; h1[1] = one; h1[2] = one; h1[3] = zero;
        h1[4] = zero; h1[5] = zero; h1[6] = zero; h1[7] = zero;

        size_t base = (size_t)(i >> 5) * 1024 + (size_t)(i & 31) * 16;
        *(bf16x8*)(pfr + base)       = h0;
        *(bf16x8*)(pfr + base + 512) = h1;
        pp[i] = fmaf(x, x, fmaf(y, y, z * z));
    }
}

// ---- Main: 2048 blocks = 128 point-blocks x 16 vert-chunks. No LDS/barriers.
// Wave w: holds vert-chunk vc's 8 A-frag tiles (256 verts) in VGPRs and
// streams G=4 point-groups (32 cols each) from the pfrag table.
// partial[vc][point] = min over the chunk's 256 verts of (v2 - 2 p.v).
__global__ __launch_bounds__(TPB) void chamfer_mfma(
    const unsigned char* __restrict__ vfr, const unsigned char* __restrict__ pfr,
    float* __restrict__ partial)
{
    const int blk  = blockIdx.x;
    const int vc   = blk & (NVC - 1);
    const int pblk = blk >> 4;                   // 0..127
    const int b    = pblk >> 5;                  // 32 point-blocks per batch
    const int t    = threadIdx.x;
    const int w    = t >> 6, L = t & 63;
    const int half = L >> 5, c = L & 31;
    const int laneoff = half * 512 + c * 16;

    // A-frags: 8 coalesced 16B/lane loads (1 KB/wave each), once per wave.
    const unsigned char* abase =
        vfr + (size_t)b * 131072 + (size_t)vc * (VT * 1024) + laneoff;
    bf16x8 av[VT];
#pragma unroll
    for (int tt = 0; tt < VT; ++tt)
        av[tt] = *(const bf16x8*)(abase + tt * 1024);

    // B-frags for this wave's 4 point-groups: issue all loads up front.
    const int pg0 = pblk * (PPB / 32) + w * G;
    bf16x8 bP[G];
#pragma unroll
    for (int g = 0; g < G; ++g)
        bP[g] = *(const bf16x8*)(pfr + (size_t)(pg0 + g) * 1024 + laneoff);

    f32x16 zeroC;
#pragma unroll
    for (int r = 0; r < 16; ++r) zeroC[r] = 0.0f;

#pragma unroll
    for (int g = 0; g < G; ++g) {
        float mn[8];
#pragma unroll
        for (int u = 0; u < 8; ++u) mn[u] = FLT_MAX;
        // 8 independent MFMAs; C-reg r is vert-row (r&3)+8*(r>>2)+4*half of
        // tile tt, col = point c -> folding across regs/tiles is a vert-min.
#pragma unroll
        for (int tt = 0; tt < VT; ++tt) {
            f32x16 C = __builtin_amdgcn_mfma_f32_32x32x16_bf16(
                av[tt], bP[g], zeroC, 0, 0, 0);
#pragma unroll
            for (int u = 0; u < 8; ++u)
                mn[u] = fminf(fminf(mn[u], C[2 * u]), C[2 * u + 1]);  // v_min3
        }
        // Fold 8 accumulators, merge halves (L and L+32 hold the same point,
        // disjoint vert rows), coalesced store by half-0 lanes.
        float m01 = fminf(fminf(mn[0], mn[1]), fminf(mn[2], mn[3]));
        float m23 = fminf(fminf(mn[4], mn[5]), fminf(mn[6], mn[7]));
        float m = fminf(m01, m23);
        m = fminf(m, __shfl_xor(m, 32, 64));
        if (L < 32)
            partial[(size_t)vc * BN + (size_t)(pg0 + g) * 32 + c] = m;
    }
}

// ---- Reduce: min over 16 vert-chunks, add pp, clamp, per-batch mean. ----
__global__ __launch_bounds__(256) void chamfer_reduce(
    const float* __restrict__ partial, const float* __restrict__ pp,
    float* __restrict__ out)
{
    const int p = blockIdx.x * 256 + threadIdx.x;
    const int b = blockIdx.x >> 6;               // 64 blocks per batch
    float m = FLT_MAX;
#pragma unroll
    for (int vc = 0; vc < NVC; ++vc)
        m = fminf(m, partial[(size_t)vc * BN + p]);
    float sum = fmaxf(m + pp[p], 0.0f);

    for (int off = 32; off > 0; off >>= 1)
        sum += __shfl_down(sum, off, 64);
    __shared__ float acc[4];
    if ((threadIdx.x & 63) == 0) acc[threadIdx.x >> 6] = sum;
    __syncthreads();
    if (threadIdx.x == 0) {
        float s = acc[0] + acc[1] + acc[2] + acc[3];
        atomicAdd(&out[b], s * (1.0f / N));
    }
}

extern "C" void kernel_launch(void* const* d_in, const int* in_sizes, int n_in,
                              void* d_out, int out_size, void* d_ws, size_t ws_size,
                              hipStream_t stream) {
    const float* src = (const float*)d_in[0];    // (B, N, 3) fp32
    const float* tv  = (const float*)d_in[1];    // (B, M, 3) fp32
    float* out = (float*)d_out;                  // (B,) fp32

    unsigned char* vfr = (unsigned char*)d_ws;                       // 512 KB
    unsigned char* pfr = vfr + VFRAG_BYTES;                          // 2 MB
    float* pp          = (float*)(pfr + PFRAG_BYTES);                // 256 KB
    float* partial     = (float*)((char*)pp + PP_BYTES);             // 4 MB

    chamfer_pre   <<<(B * M) / 256 + BN / 256, 256, 0, stream>>>(src, tv, vfr, pfr, pp, out);
    chamfer_mfma  <<<NVC * NPB, TPB, 0, stream>>>(vfr, pfr, partial);
    chamfer_reduce<<<BN / 256, 256, 0, stream>>>(partial, pp, out);
}

// Round 2
// 69.490 us; speedup vs baseline: 1.1186x; 1.1186x over previous
//
#include <hip/hip_runtime.h>
#include <float.h>

// ChamferLoss via MFMA, R12: two dispatches total.
// B=4, N=16384, M=4096, fp32 in/out.
// loss[b] = (1/N) * sum_n min_m max(||p_bn - v_bm||^2, 0)
//
// d2 = pp + (v2 - 2 p.v). Bracket on the MATRIX pipe via split-bf16 in K=16
// of mfma_f32_32x32x16_bf16 (encoding validated R6-R11, absmax 0.0):
//   A row (VERT):   [-2vh x3, -2vh x3, -2vl x3, v2h, v2l, 0...]
//   B col (POINT):  [ph x3, pl x3, ph x3, 1, 1, 0...]
//
// R12: R0/R11 showed total-minus-fill constant at ~35.5us -> suspect
// dispatch overhead + buffer round-trips, not MFMA math. So: (1) point
// B-frags are built IN-KERNEL (R10-style, validated) -- no 2MB pfrag table;
// (2) the min over ALL of M completes inside the main kernel (two waves
// split M 64-tiles each, merge via LDS) -- no 4MB partial buffer; (3) the
// final sum reproduces the R1 reduce's tree bit-for-bit (same lane<->point
// mapping, same shfl_down order, same acc[4] order, one atomicAdd per 256
// points) and runs in the main kernel's epilogue -- no reduce dispatch.
// Main-kernel floor: MFMA 3.4us, L2 A-frag stream 128MB = 3.7us, VALU 1.7us
// (hidden at 2 waves/SIMD, m114 co-issue).

typedef __bf16 bf16x8 __attribute__((ext_vector_type(8)));
typedef float  f32x16 __attribute__((ext_vector_type(16)));

constexpr int B = 4, N = 16384, M = 4096;
constexpr int BN = B * N;                 // 65536 points total
constexpr int TILES = M / 32;             // 128 vert tiles per batch
constexpr int HT = TILES / 2;             // 64 tiles per M-half
constexpr int TPB = 512;                  // 8 waves: 4 point-spans x 2 M-halves
constexpr int PPB = 256;                  // points per block
constexpr int NPB = BN / PPB;             // 256 blocks

constexpr size_t VFRAG_BYTES = (size_t)B * M * 32;   // 512 KB vert A-frags

// ---- Pre-pass: per-vert A-frag K-vectors (R11 layout); zero out[]. ----
// Vert m of batch b -> byte offset b*131072 + (m>>5)*1024 + khalf*512 + (m&31)*16
__global__ __launch_bounds__(256) void chamfer_pre(
    const float* __restrict__ tv, unsigned char* __restrict__ vfr,
    float* __restrict__ out)
{
    if (blockIdx.x == 0 && threadIdx.x < B) out[threadIdx.x] = 0.0f;
    int i = blockIdx.x * 256 + threadIdx.x;          // 0..B*M-1
    float x = tv[3 * i + 0], y = tv[3 * i + 1], z = tv[3 * i + 2];
    __bf16 xh = (__bf16)x, yh = (__bf16)y, zh = (__bf16)z;
    float xhf = (float)xh, yhf = (float)yh, zhf = (float)zh;
    __bf16 xl = (__bf16)(x - xhf), yl = (__bf16)(y - yhf), zl = (__bf16)(z - zhf);
    float v2 = fmaf(x, x, fmaf(y, y, z * z));
    __bf16 v2h = (__bf16)v2;
    __bf16 v2l = (__bf16)(v2 - (float)v2h);
    __bf16 zero = (__bf16)0.0f;

    bf16x8 h0, h1;
    h0[0] = (__bf16)(-2.0f * xhf); h0[1] = (__bf16)(-2.0f * yhf);
    h0[2] = (__bf16)(-2.0f * zhf);
    h0[3] = h0[0]; h0[4] = h0[1]; h0[5] = h0[2];
    h0[6] = (__bf16)(-2.0f * (float)xl); h0[7] = (__bf16)(-2.0f * (float)yl);
    h1[0] = (__bf16)(-2.0f * (float)zl); h1[1] = v2h; h1[2] = v2l;
    h1[3] = zero; h1[4] = zero; h1[5] = zero; h1[6] = zero; h1[7] = zero;

    int m = i & (M - 1);
    size_t base = (size_t)(i >> 12) * 131072 + (size_t)(m >> 5) * 1024
                + (size_t)(m & 31) * 16;
    *(bf16x8*)(vfr + base)       = h0;
    *(bf16x8*)(vfr + base + 512) = h1;
}

// ---- Main: 256 blocks x 512 threads. Block = 256 consecutive points.
// Wave w: point-span s = w&3 (64 points, two 32-col groups), M-half h = w>>2
// (64 vert tiles). B-frags built in-reg from src; A-frags streamed from vfr.
// The two M-half waves min-merge in LDS; epilogue = R1 reduce tree verbatim.
__global__ __launch_bounds__(TPB) void chamfer_main(
    const float* __restrict__ src, const unsigned char* __restrict__ vfr,
    float* __restrict__ out)
{
    const int pblk = blockIdx.x;
    const int b    = pblk >> 6;                  // 64 blocks per batch
    const int t    = threadIdx.x;
    const int w    = t >> 6, L = t & 63;
    const int s    = w & 3, h = w >> 2;
    const int half = L >> 5, c = L & 31;
    const int laneoff = half * 512 + c * 16;

    // Two points per lane: group0 = span base + c, group1 = +32.
    const int P0 = pblk * PPB + s * 64;
    const int p0 = P0 + c, p1 = P0 + 32 + c;
    float x0 = src[3 * p0], y0 = src[3 * p0 + 1], z0 = src[3 * p0 + 2];
    float x1 = src[3 * p1], y1 = src[3 * p1 + 1], z1 = src[3 * p1 + 2];
    float pp0 = fmaf(x0, x0, fmaf(y0, y0, z0 * z0));
    float pp1 = fmaf(x1, x1, fmaf(y1, y1, z1 * z1));

    __bf16 one = (__bf16)1.0f, zero = (__bf16)0.0f;
    bf16x8 bP0, bP1;
    {
        __bf16 xh = (__bf16)x0, yh = (__bf16)y0, zh = (__bf16)z0;
        __bf16 xl = (__bf16)(x0 - (float)xh), yl = (__bf16)(y0 - (float)yh),
               zl = (__bf16)(z0 - (float)zh);
        if (half == 0) { bP0[0]=xh; bP0[1]=yh; bP0[2]=zh; bP0[3]=xl; bP0[4]=yl; bP0[5]=zl; bP0[6]=xh; bP0[7]=yh; }
        else { bP0[0]=zh; bP0[1]=one; bP0[2]=one; bP0[3]=zero; bP0[4]=zero; bP0[5]=zero; bP0[6]=zero; bP0[7]=zero; }
    }
    {
        __bf16 xh = (__bf16)x1, yh = (__bf16)y1, zh = (__bf16)z1;
        __bf16 xl = (__bf16)(x1 - (float)xh), yl = (__bf16)(y1 - (float)yh),
               zl = (__bf16)(z1 - (float)zh);
        if (half == 0) { bP1[0]=xh; bP1[1]=yh; bP1[2]=zh; bP1[3]=xl; bP1[4]=yl; bP1[5]=zl; bP1[6]=xh; bP1[7]=yh; }
        else { bP1[0]=zh; bP1[1]=one; bP1[2]=one; bP1[3]=zero; bP1[4]=zero; bP1[5]=zero; bP1[6]=zero; bP1[7]=zero; }
    }

    f32x16 zeroC;
#pragma unroll
    for (int r = 0; r < 16; ++r) zeroC[r] = 0.0f;
    float mn0[8], mn1[8];
#pragma unroll
    for (int u = 0; u < 8; ++u) { mn0[u] = FLT_MAX; mn1[u] = FLT_MAX; }

    // Stream this M-half's 64 vert tiles: 1 global_load_dwordx4 + 2 MFMA +
    // 16 v_min3 per tile. C-reg r is vert-row (r&3)+8*(r>>2)+4*half of the
    // tile, col = the group's point c -> folding across regs/tiles is a
    // legal vert-min.
    const unsigned char* abase =
        vfr + (size_t)b * 131072 + (size_t)h * (HT * 1024) + laneoff;
#pragma unroll 8
    for (int tt = 0; tt < HT; ++tt) {
        bf16x8 av = *(const bf16x8*)(abase + tt * 1024);
        f32x16 C0 = __builtin_amdgcn_mfma_f32_32x32x16_bf16(av, bP0, zeroC, 0, 0, 0);
        f32x16 C1 = __builtin_amdgcn_mfma_f32_32x32x16_bf16(av, bP1, zeroC, 0, 0, 0);
#pragma unroll
        for (int u = 0; u < 8; ++u) {
            mn0[u] = fminf(fminf(mn0[u], C0[2 * u]), C0[2 * u + 1]);   // v_min3
            mn1[u] = fminf(fminf(mn1[u], C1[2 * u]), C1[2 * u + 1]);
        }
    }

    // Fold 8 accumulators per group; merge lane-halves (L, L+32 share a
    // point, disjoint vert rows); lane L then holds point P0 + L's half-M min.
    float a01 = fminf(fminf(mn0[0], mn0[1]), fminf(mn0[2], mn0[3]));
    float a23 = fminf(fminf(mn0[4], mn0[5]), fminf(mn0[6], mn0[7]));
    float m0 = fminf(a01, a23);
    m0 = fminf(m0, __shfl_xor(m0, 32, 64));
    float b01 = fminf(fminf(mn1[0], mn1[1]), fminf(mn1[2], mn1[3]));
    float b23 = fminf(fminf(mn1[4], mn1[5]), fminf(mn1[6], mn1[7]));
    float m1 = fminf(b01, b23);
    m1 = fminf(m1, __shfl_xor(m1, 32, 64));
    float m  = half ? m1 : m0;
    float pp = half ? pp1 : pp0;

    // Merge the two M-halves (wave w and w+4 hold the same points).
    __shared__ float lds_m[TPB];
    __shared__ float acc[8];
    lds_m[t] = m;
    __syncthreads();

    float sum = 0.0f;
    if (w < 4) {
        float mm = fminf(m, lds_m[t + 256]);
        sum = fmaxf(mm + pp, 0.0f);
    }
    // Same tree as the R1 reduce: shfl_down over 64 lanes in lane order.
    for (int off = 32; off > 0; off >>= 1)
        sum += __shfl_down(sum, off, 64);
    if (L == 0) acc[w] = sum;
    __syncthreads();
    if (t == 0) {
        float ssum = acc[0] + acc[1] + acc[2] + acc[3];
        atomicAdd(&out[b], ssum * (1.0f / N));
    }
}

extern "C" void kernel_launch(void* const* d_in, const int* in_sizes, int n_in,
                              void* d_out, int out_size, void* d_ws, size_t ws_size,
                              hipStream_t stream) {
    const float* src = (const float*)d_in[0];    // (B, N, 3) fp32
    const float* tv  = (const float*)d_in[1];    // (B, M, 3) fp32
    float* out = (float*)d_out;                  // (B,) fp32
    unsigned char* vfr = (unsigned char*)d_ws;   // 512 KB vert A-frags

    chamfer_pre <<<(B * M) / 256, 256, 0, stream>>>(tv, vfr, out);
    chamfer_main<<<NPB, TPB, 0, stream>>>(src, vfr, out);
}

// Round 3
// 66.827 us; speedup vs baseline: 1.1631x; 1.0399x over previous
//
#include <hip/hip_runtime.h>
#include <float.h>

// ChamferLoss via MFMA, R13: ONE real dispatch (+ 16-byte memset node).
// B=4, N=16384, M=4096, fp32 in/out.
// loss[b] = (1/N) * sum_n min_m max(||p_bn - v_bm||^2, 0)
//
// d2 = pp + (v2 - 2 p.v). Bracket on the MATRIX pipe via split-bf16 in K=16
// of mfma_f32_32x32x16_bf16 (encoding validated R6-R12, absmax 0.0):
//   A row (VERT):   [-2vh x3, -2vh x3, -2vl x3, v2h, v2l, 0...]
//   B col (POINT):  [ph x3, pl x3, ph x3, 1, 1, 0...]
//
// R13: R12 confirmed the addressable cost is dispatches + buffer traffic.
// Changes: (1) pre-pass kernel replaced by hipMemsetAsync(out,0,16) -- a
// cheap graph memset node; (2) vert A-frags built IN-KERNEL into LDS (two
// 64 KB chunks of 2048 verts), removing the 512 KB vfr table and its 128 MB
// L2 restream -- main loop is now pure ds_read_b128 + MFMA + v_min3,
// MFMA-bound (~3.4us floor; LDS stream 1.7-2.6us overlapped); (3) epilogue
// reuses the frag LDS. fmin is exact under reordering, and the summation
// tree (lane<->point map, shfl_down order, acc order, one atomicAdd per 256
// points) is kept verbatim from R12 -> absmax 0.0 preserved.

typedef __bf16 bf16x8 __attribute__((ext_vector_type(8)));
typedef float  f32x16 __attribute__((ext_vector_type(16)));

constexpr int B = 4, N = 16384, M = 4096;
constexpr int BN = B * N;                 // 65536 points total
constexpr int TPB = 512;                  // 8 waves: 4 point-spans x 2 M-halves
constexpr int PPB = 256;                  // points per block
constexpr int NPB = BN / PPB;             // 256 blocks = 1/CU
constexpr int CHUNK = 2048;               // verts per LDS pass (64 KB frags)
constexpr int NCH = M / CHUNK;            // 2 chunks
constexpr int CT = CHUNK / 32;            // 64 tiles per chunk
constexpr int HT = CT / 2;                // 32 tiles per wave per chunk

// ---- Fused kernel: 256 blocks x 512 threads. Block = 256 consecutive
// points of batch b. Per chunk of 2048 verts: all threads build A-frags in
// LDS (same arithmetic as the R11 pre-pass, byte-identical frags), then
// wave w (point-span s=w&3, chunk-half h=w>>2) runs 32 tiles of
// ds_read_b128 + 2 MFMA + 16 v_min3. Epilogue = R12 tree verbatim.
__global__ __launch_bounds__(TPB) void chamfer_fused(
    const float* __restrict__ src, const float* __restrict__ tv,
    float* __restrict__ out)
{
    __shared__ uint4 lds4[4096];                 // 64 KB, reused by epilogue
    char* ldsc = (char*)lds4;

    const int pblk = blockIdx.x;
    const int b    = pblk >> 6;                  // 64 blocks per batch
    const int t    = threadIdx.x;
    const int w    = t >> 6, L = t & 63;
    const int s    = w & 3, h = w >> 2;
    const int half = L >> 5, c = L & 31;
    const int laneoff = half * 512 + c * 16;

    // Two points per lane: group0 = span base + c, group1 = +32.
    const int P0 = pblk * PPB + s * 64;
    const int p0 = P0 + c, p1 = P0 + 32 + c;
    float x0 = src[3 * p0], y0 = src[3 * p0 + 1], z0 = src[3 * p0 + 2];
    float x1 = src[3 * p1], y1 = src[3 * p1 + 1], z1 = src[3 * p1 + 2];
    float pp0 = fmaf(x0, x0, fmaf(y0, y0, z0 * z0));
    float pp1 = fmaf(x1, x1, fmaf(y1, y1, z1 * z1));

    __bf16 one = (__bf16)1.0f, zero = (__bf16)0.0f;
    bf16x8 bP0, bP1;
    {
        __bf16 xh = (__bf16)x0, yh = (__bf16)y0, zh = (__bf16)z0;
        __bf16 xl = (__bf16)(x0 - (float)xh), yl = (__bf16)(y0 - (float)yh),
               zl = (__bf16)(z0 - (float)zh);
        if (half == 0) { bP0[0]=xh; bP0[1]=yh; bP0[2]=zh; bP0[3]=xl; bP0[4]=yl; bP0[5]=zl; bP0[6]=xh; bP0[7]=yh; }
        else { bP0[0]=zh; bP0[1]=one; bP0[2]=one; bP0[3]=zero; bP0[4]=zero; bP0[5]=zero; bP0[6]=zero; bP0[7]=zero; }
    }
    {
        __bf16 xh = (__bf16)x1, yh = (__bf16)y1, zh = (__bf16)z1;
        __bf16 xl = (__bf16)(x1 - (float)xh), yl = (__bf16)(y1 - (float)yh),
               zl = (__bf16)(z1 - (float)zh);
        if (half == 0) { bP1[0]=xh; bP1[1]=yh; bP1[2]=zh; bP1[3]=xl; bP1[4]=yl; bP1[5]=zl; bP1[6]=xh; bP1[7]=yh; }
        else { bP1[0]=zh; bP1[1]=one; bP1[2]=one; bP1[3]=zero; bP1[4]=zero; bP1[5]=zero; bP1[6]=zero; bP1[7]=zero; }
    }

    f32x16 zeroC;
#pragma unroll
    for (int r = 0; r < 16; ++r) zeroC[r] = 0.0f;
    float mn0[8], mn1[8];
#pragma unroll
    for (int u = 0; u < 8; ++u) { mn0[u] = FLT_MAX; mn1[u] = FLT_MAX; }

    for (int ch = 0; ch < NCH; ++ch) {
        if (ch) __syncthreads();                 // drain prior chunk's reads

        // ---- Build this chunk's A-frags (4 verts per thread, stride 512).
        // Same ops as the validated pre-pass -> byte-identical fragments.
#pragma unroll
        for (int k = 0; k < 4; ++k) {
            int ml = t + k * 512;                // vert-in-chunk 0..2047
            int i  = b * M + ch * CHUNK + ml;    // global vert index
            float x = tv[3 * i + 0], y = tv[3 * i + 1], z = tv[3 * i + 2];
            __bf16 xh = (__bf16)x, yh = (__bf16)y, zh = (__bf16)z;
            float xhf = (float)xh, yhf = (float)yh, zhf = (float)zh;
            __bf16 xl = (__bf16)(x - xhf), yl = (__bf16)(y - yhf),
                   zl = (__bf16)(z - zhf);
            float v2 = fmaf(x, x, fmaf(y, y, z * z));
            __bf16 v2h = (__bf16)v2;
            __bf16 v2l = (__bf16)(v2 - (float)v2h);

            bf16x8 h0, h1;
            h0[0] = (__bf16)(-2.0f * xhf); h0[1] = (__bf16)(-2.0f * yhf);
            h0[2] = (__bf16)(-2.0f * zhf);
            h0[3] = h0[0]; h0[4] = h0[1]; h0[5] = h0[2];
            h0[6] = (__bf16)(-2.0f * (float)xl); h0[7] = (__bf16)(-2.0f * (float)yl);
            h1[0] = (__bf16)(-2.0f * (float)zl); h1[1] = v2h; h1[2] = v2l;
            h1[3] = zero; h1[4] = zero; h1[5] = zero; h1[6] = zero; h1[7] = zero;

            size_t base = (size_t)(ml >> 5) * 1024 + (size_t)(ml & 31) * 16;
            *(bf16x8*)(ldsc + base)       = h0;
            *(bf16x8*)(ldsc + base + 512) = h1;
        }
        __syncthreads();

        // ---- 32 tiles for this wave's chunk-half: 1 ds_read_b128 + 2 MFMA
        // + 16 v_min3. C-reg r is vert-row (r&3)+8*(r>>2)+4*half of the
        // tile, col = point c -> folding across regs/tiles/chunks is a
        // legal (exact) vert-min.
        const char* abase = ldsc + (size_t)h * (HT * 1024) + laneoff;
#pragma unroll 8
        for (int tt = 0; tt < HT; ++tt) {
            bf16x8 av = *(const bf16x8*)(abase + tt * 1024);
            f32x16 C0 = __builtin_amdgcn_mfma_f32_32x32x16_bf16(av, bP0, zeroC, 0, 0, 0);
            f32x16 C1 = __builtin_amdgcn_mfma_f32_32x32x16_bf16(av, bP1, zeroC, 0, 0, 0);
#pragma unroll
            for (int u = 0; u < 8; ++u) {
                mn0[u] = fminf(fminf(mn0[u], C0[2 * u]), C0[2 * u + 1]);  // v_min3
                mn1[u] = fminf(fminf(mn1[u], C1[2 * u]), C1[2 * u + 1]);
            }
        }
    }

    // ---- Fold 8 accumulators per group; merge lane-halves (L, L+32 share
    // a point, disjoint vert rows); lane L holds point P0+L's half-M min.
    float a01 = fminf(fminf(mn0[0], mn0[1]), fminf(mn0[2], mn0[3]));
    float a23 = fminf(fminf(mn0[4], mn0[5]), fminf(mn0[6], mn0[7]));
    float m0 = fminf(a01, a23);
    m0 = fminf(m0, __shfl_xor(m0, 32, 64));
    float b01 = fminf(fminf(mn1[0], mn1[1]), fminf(mn1[2], mn1[3]));
    float b23 = fminf(fminf(mn1[4], mn1[5]), fminf(mn1[6], mn1[7]));
    float m1 = fminf(b01, b23);
    m1 = fminf(m1, __shfl_xor(m1, 32, 64));
    float m  = half ? m1 : m0;
    float pp = half ? pp1 : pp0;

    // ---- Merge the two M-halves (wave w and w+4 hold the same points),
    // then the R12 summation tree verbatim. Reuse the frag LDS.
    __syncthreads();                             // frag reads done; safe to reuse
    float* lf = (float*)ldsc;                    // lf[0..511] = lds_m
    float* acc = lf + 512;                       // lf[512..519] = acc
    lf[t] = m;
    __syncthreads();

    float sum = 0.0f;
    if (w < 4) {
        float mm = fminf(m, lf[t + 256]);
        sum = fmaxf(mm + pp, 0.0f);
    }
    for (int off = 32; off > 0; off >>= 1)
        sum += __shfl_down(sum, off, 64);
    if (L == 0) acc[w] = sum;
    __syncthreads();
    if (t == 0) {
        float ssum = acc[0] + acc[1] + acc[2] + acc[3];
        atomicAdd(&out[b], ssum * (1.0f / N));
    }
}

extern "C" void kernel_launch(void* const* d_in, const int* in_sizes, int n_in,
                              void* d_out, int out_size, void* d_ws, size_t ws_size,
                              hipStream_t stream) {
    const float* src = (const float*)d_in[0];    // (B, N, 3) fp32
    const float* tv  = (const float*)d_in[1];    // (B, M, 3) fp32
    float* out = (float*)d_out;                  // (B,) fp32

    hipMemsetAsync(out, 0, out_size, stream);    // graph-capturable memset node
    chamfer_fused<<<NPB, TPB, 0, stream>>>(src, tv, out);
}